// Round 7
// baseline (258.298 us; speedup 1.0000x reference)
//
#include <hip/hip_runtime.h>
#include <hip/hip_fp16.h>
#include <math.h>

#define NN 50000
#define EE 800000
#define E2 (EE + NN)
#define FIN 128
#define HC 256
#define HID 128
#define NCLS 10
#define NEG 0.2f

typedef _Float16 f16x8 __attribute__((ext_vector_type(8)));
typedef float f32x4 __attribute__((ext_vector_type(4)));

// fp32 acc += fp16(lo/hi of u) * fp32 w   (VOP3P mixed-precision FMA)
#define FMA_MIX_LO(acc, u, w) \
    asm("v_fma_mix_f32 %0, %1, %2, %0 op_sel:[0,0,0] op_sel_hi:[1,0,0]" \
        : "+v"(acc) : "v"(u), "v"(w))
#define FMA_MIX_HI(acc, u, w) \
    asm("v_fma_mix_f32 %0, %1, %2, %0 op_sel:[1,0,0] op_sel_hi:[1,0,0]" \
        : "+v"(acc) : "v"(u), "v"(w))

__device__ inline f16x8 cvt8(float4 a, float4 b) {
    f16x8 r;
    r[0] = (_Float16)a.x; r[1] = (_Float16)a.y; r[2] = (_Float16)a.z; r[3] = (_Float16)a.w;
    r[4] = (_Float16)b.x; r[5] = (_Float16)b.y; r[6] = (_Float16)b.z; r[7] = (_Float16)b.w;
    return r;
}

// ---------------- prep: WgT_h[256][128], WcT_h[128][256] (fp16, transposed) ----------------
__global__ __launch_bounds__(256) void prep_kernel(const float* __restrict__ Wg,
                                                   const float* __restrict__ Wc,
                                                   ushort* __restrict__ wgt,
                                                   ushort* __restrict__ wct) {
    int i = blockIdx.x * 256 + threadIdx.x;
    if (i < HC * FIN) {
        int c = i & 255, k = i >> 8;
        wgt[c * FIN + k] = __half_as_ushort(__float2half(Wg[i]));
        int c2 = i & 127, k2 = i >> 7;
        wct[c2 * HC + k2] = __half_as_ushort(__float2half(Wc[i]));
    }
}

// ---------------- GEMM1 (MFMA): h = x@Wg -> fp16 linear (LDS-staged store) ----------------
__global__ __launch_bounds__(256) void gemm1_mfma(const float* __restrict__ x,
                                                  const ushort* __restrict__ wgt,
                                                  const float* __restrict__ att_s,
                                                  const float* __restrict__ att_d,
                                                  ushort* __restrict__ h_half,
                                                  float* __restrict__ a_s,
                                                  float* __restrict__ a_d) {
    __shared__ ushort hs[16][264];   // +8 pad: 4-way max bank aliasing on b16 writes
    const int t = threadIdx.x;
    const int w  = t >> 6;
    const int l  = t & 63;
    const int lr = l & 15;
    const int lg = l >> 4;
    const int rr = t >> 4;          // readout row
    const int rc = (t & 15) * 8;    // readout col (ushort)

    f16x8 bf[4][4];
#pragma unroll
    for (int ct = 0; ct < 4; ++ct)
#pragma unroll
        for (int ks = 0; ks < 4; ++ks)
            bf[ct][ks] = *(const f16x8*)(wgt + (size_t)(64 * w + 16 * ct + lr) * FIN + ks * 32 + 8 * lg);

    float asv[4], adv[4];
#pragma unroll
    for (int ct = 0; ct < 4; ++ct) {
        asv[ct] = att_s[w * 64 + 16 * ct + lr];
        adv[ct] = att_d[w * 64 + 16 * ct + lr];
    }

    for (int rt = blockIdx.x; rt < 3125; rt += gridDim.x) {
        const int r0 = rt * 16;
        f32x4 acc[4];
#pragma unroll
        for (int ct = 0; ct < 4; ++ct) acc[ct] = (f32x4){0.f, 0.f, 0.f, 0.f};

#pragma unroll
        for (int ks = 0; ks < 4; ++ks) {
            const float4* xp = (const float4*)(x + (size_t)(r0 + lr) * FIN + ks * 32 + 8 * lg);
            f16x8 af = cvt8(xp[0], xp[1]);
#pragma unroll
            for (int ct = 0; ct < 4; ++ct)
                acc[ct] = __builtin_amdgcn_mfma_f32_16x16x32_f16(af, bf[ct][ks], acc[ct], 0, 0, 0);
        }
#pragma unroll
        for (int j = 0; j < 4; ++j) {
            const int row = r0 + 4 * lg + j;
#pragma unroll
            for (int ct = 0; ct < 4; ++ct)
                hs[4 * lg + j][64 * w + 16 * ct + lr] = __half_as_ushort(__float2half(acc[ct][j]));
            float ps = 0.f, pd = 0.f;
#pragma unroll
            for (int ct = 0; ct < 4; ++ct) {
                ps += acc[ct][j] * asv[ct];
                pd += acc[ct][j] * adv[ct];
            }
#pragma unroll
            for (int m = 8; m >= 1; m >>= 1) {
                ps += __shfl_xor(ps, m, 64);
                pd += __shfl_xor(pd, m, 64);
            }
            if (lr == 0) {
                a_s[row * 4 + w] = ps;
                a_d[row * 4 + w] = pd;
            }
        }
        __syncthreads();
        // coalesced write: 2 passes of 16 rows x 128 ushorts
        *(uint4*)(h_half + (size_t)(r0 + rr) * HC + rc)       = *(const uint4*)&hs[rr][rc];
        *(uint4*)(h_half + (size_t)(r0 + rr) * HC + rc + 128) = *(const uint4*)&hs[rr][rc + 128];
        __syncthreads();
    }
}

// ---------------- GEMM2 (MFMA): xw = xg(fp16)@Wc -> fp16 (LDS-staged store) ----------------
__global__ __launch_bounds__(256) void gemm2_mfma(const ushort* __restrict__ xg,
                                                  const ushort* __restrict__ wct,
                                                  ushort* __restrict__ xw) {
    __shared__ ushort hs[16][136];
    const int t = threadIdx.x;
    const int w  = t >> 6;
    const int l  = t & 63;
    const int lr = l & 15;
    const int lg = l >> 4;
    const int rr = t >> 4;
    const int rc = (t & 15) * 8;

    f16x8 bf[2][8];
#pragma unroll
    for (int ct = 0; ct < 2; ++ct)
#pragma unroll
        for (int ks = 0; ks < 8; ++ks)
            bf[ct][ks] = *(const f16x8*)(wct + (size_t)(32 * w + 16 * ct + lr) * HC + ks * 32 + 8 * lg);

    for (int rt = blockIdx.x; rt < 3125; rt += gridDim.x) {
        const int r0 = rt * 16;
        f32x4 acc[2];
        acc[0] = (f32x4){0.f, 0.f, 0.f, 0.f};
        acc[1] = (f32x4){0.f, 0.f, 0.f, 0.f};
#pragma unroll
        for (int ks = 0; ks < 8; ++ks) {
            f16x8 af = *(const f16x8*)(xg + (size_t)(r0 + lr) * HC + ks * 32 + 8 * lg);
            acc[0] = __builtin_amdgcn_mfma_f32_16x16x32_f16(af, bf[0][ks], acc[0], 0, 0, 0);
            acc[1] = __builtin_amdgcn_mfma_f32_16x16x32_f16(af, bf[1][ks], acc[1], 0, 0, 0);
        }
#pragma unroll
        for (int j = 0; j < 4; ++j) {
#pragma unroll
            for (int ct = 0; ct < 2; ++ct)
                hs[4 * lg + j][32 * w + 16 * ct + lr] = __half_as_ushort(__float2half(acc[ct][j]));
        }
        __syncthreads();
        *(uint4*)(xw + (size_t)(r0 + rr) * HID + rc) = *(const uint4*)&hs[rr][rc];
        __syncthreads();
    }
}

// ---------------- CSR build ----------------
__global__ __launch_bounds__(256) void deg_kernel(const int* __restrict__ ei, int* __restrict__ deg) {
    int e4 = blockIdx.x * 256 + threadIdx.x;
    if (e4 * 4 >= EE) return;
    int4 d = ((const int4*)(ei + EE))[e4];
    atomicAdd(&deg[d.x], 1);
    atomicAdd(&deg[d.y], 1);
    atomicAdd(&deg[d.z], 1);
    atomicAdd(&deg[d.w], 1);
}

__global__ __launch_bounds__(256) void scan_a(const int* __restrict__ deg, int* __restrict__ row_start,
                                              int* __restrict__ blocksum) {
    __shared__ int sh[256];
    int t = threadIdx.x;
    int i = blockIdx.x * 256 + t;
    int v = (i < NN) ? (deg[i] + 1) : 0;
    sh[t] = v;
    __syncthreads();
#pragma unroll
    for (int off = 1; off < 256; off <<= 1) {
        int y = (t >= off) ? sh[t - off] : 0;
        __syncthreads();
        sh[t] += y;
        __syncthreads();
    }
    if (i < NN) row_start[i] = sh[t] - v;
    if (t == 255) blocksum[blockIdx.x] = sh[255];
}

__global__ __launch_bounds__(256) void scan_b(int* __restrict__ bs, int nb) {
    __shared__ int sh[256];
    int t = threadIdx.x;
    int v = (t < nb) ? bs[t] : 0;
    sh[t] = v;
    __syncthreads();
#pragma unroll
    for (int off = 1; off < 256; off <<= 1) {
        int y = (t >= off) ? sh[t - off] : 0;
        __syncthreads();
        sh[t] += y;
        __syncthreads();
    }
    if (t < nb) bs[t] = sh[t] - v;
}

__global__ __launch_bounds__(256) void scan_c(int* __restrict__ row_start, const int* __restrict__ bs) {
    int i = blockIdx.x * 256 + threadIdx.x;
    if (i < NN) row_start[i] += bs[blockIdx.x];
    if (i == 0) row_start[NN] = E2;
}

__global__ __launch_bounds__(256) void scatter_kernel(const int* __restrict__ ei,
                                                      const int* __restrict__ row_start,
                                                      int* __restrict__ cursor,
                                                      int* __restrict__ csr_src) {
    int e = blockIdx.x * 256 + threadIdx.x;
    if (e >= E2) return;
    int src, dst;
    if (e < EE) { src = ei[e]; dst = ei[EE + e]; }
    else        { src = dst = e - EE; }
    int pos = row_start[dst] + atomicAdd(&cursor[dst], 1);
    csr_src[pos] = src;
}

// ---------------- fused GAT: two-phase, packed ds_read_b64, fma_mix, unroll-8 ----------------
__global__ __launch_bounds__(256) void gat_half(const ushort* __restrict__ h_half,
                                                const float* __restrict__ a_s,
                                                const float* __restrict__ a_d,
                                                const int* __restrict__ row_start,
                                                const int* __restrict__ csr_src,
                                                const float* __restrict__ bg,
                                                ushort* __restrict__ xg,
                                                float* __restrict__ dinv) {
    __shared__ int2 lds_ow[4][4 * 65];   // [wid][comp*65 + j] = {byte_off, w_bits}
    const int wid  = threadIdx.x >> 6;
    const int lane = threadIdx.x & 63;
    const int node = blockIdx.x * 4 + wid;
    if (node >= NN) return;
    const int s0 = row_start[node], s1 = row_start[node + 1];
    const float4 ad = ((const float4*)a_d)[node];
    const int comp = lane >> 4;

    float den0 = 0.f, den1 = 0.f, den2 = 0.f, den3 = 0.f;
    float a0 = 0.f, a1 = 0.f, a2 = 0.f, a3 = 0.f;
    const char* hbase = (const char*)h_half;
    const uint lane8 = (uint)lane * 8;
    const int2* myow = &lds_ow[wid][comp * 65];

#define GAT_BODY(OW)                                             \
    {                                                            \
        uint2 u = *(const uint2*)(hbase + ((uint)(OW).x + lane8)); \
        float ww = __int_as_float((OW).y);                       \
        FMA_MIX_LO(a0, u.x, ww); FMA_MIX_HI(a1, u.x, ww);        \
        FMA_MIX_LO(a2, u.y, ww); FMA_MIX_HI(a3, u.y, ww);        \
    }

    for (int e = s0; e < s1; e += 64) {
        const int m = min(64, s1 - e);
        if (lane < m) {
            int src = csr_src[e + lane];
            float4 as = ((const float4*)a_s)[src];
            float v0 = as.x + ad.x; v0 = v0 > 0.f ? v0 : NEG * v0;
            float v1 = as.y + ad.y; v1 = v1 > 0.f ? v1 : NEG * v1;
            float v2 = as.z + ad.z; v2 = v2 > 0.f ? v2 : NEG * v2;
            float v3 = as.w + ad.w; v3 = v3 > 0.f ? v3 : NEG * v3;
            float e0 = __expf(v0); den0 += e0;
            float e1 = __expf(v1); den1 += e1;
            float e2 = __expf(v2); den2 += e2;
            float e3 = __expf(v3); den3 += e3;
            int boff = src * 512;
            lds_ow[wid][0 * 65 + lane] = make_int2(boff, __float_as_int(e0));
            lds_ow[wid][1 * 65 + lane] = make_int2(boff, __float_as_int(e1));
            lds_ow[wid][2 * 65 + lane] = make_int2(boff, __float_as_int(e2));
            lds_ow[wid][3 * 65 + lane] = make_int2(boff, __float_as_int(e3));
        }
        asm volatile("s_waitcnt lgkmcnt(0)" ::: "memory");
        int j = 0;
        for (; j + 8 <= m; j += 8) {
            int2 ow0 = myow[j];
            int2 ow1 = myow[j + 1];
            int2 ow2 = myow[j + 2];
            int2 ow3 = myow[j + 3];
            int2 ow4 = myow[j + 4];
            int2 ow5 = myow[j + 5];
            int2 ow6 = myow[j + 6];
            int2 ow7 = myow[j + 7];
            GAT_BODY(ow0); GAT_BODY(ow1); GAT_BODY(ow2); GAT_BODY(ow3);
            GAT_BODY(ow4); GAT_BODY(ow5); GAT_BODY(ow6); GAT_BODY(ow7);
        }
        for (; j + 4 <= m; j += 4) {
            int2 ow0 = myow[j];
            int2 ow1 = myow[j + 1];
            int2 ow2 = myow[j + 2];
            int2 ow3 = myow[j + 3];
            GAT_BODY(ow0); GAT_BODY(ow1); GAT_BODY(ow2); GAT_BODY(ow3);
        }
        for (; j < m; ++j) {
            int2 ow = myow[j];
            GAT_BODY(ow);
        }
        asm volatile("" ::: "memory");
    }
#undef GAT_BODY
#pragma unroll
    for (int m = 32; m >= 1; m >>= 1) {
        den0 += __shfl_xor(den0, m, 64);
        den1 += __shfl_xor(den1, m, 64);
        den2 += __shfl_xor(den2, m, 64);
        den3 += __shfl_xor(den3, m, 64);
    }
    float d = (comp == 0) ? den0 : (comp == 1) ? den1 : (comp == 2) ? den2 : den3;
    float4 b = ((const float4*)bg)[lane];
    float o0 = a0 / d + b.x;
    float o1 = a1 / d + b.y;
    float o2 = a2 / d + b.z;
    float o3 = a3 / d + b.w;
    o0 = o0 > 0.f ? o0 : __expf(o0) - 1.f;
    o1 = o1 > 0.f ? o1 : __expf(o1) - 1.f;
    o2 = o2 > 0.f ? o2 : __expf(o2) - 1.f;
    o3 = o3 > 0.f ? o3 : __expf(o3) - 1.f;
    ushort4 u;
    u.x = __half_as_ushort(__float2half(o0));
    u.y = __half_as_ushort(__float2half(o1));
    u.z = __half_as_ushort(__float2half(o2));
    u.w = __half_as_ushort(__float2half(o3));
    ((ushort4*)xg)[(size_t)node * 64 + lane] = u;
    if (lane == 0) dinv[node] = rsqrtf((float)(s1 - s0));
}

// ---------------- GCN + classifier head fused, packed b64 + fma_mix, unroll-8 ----------------
__global__ __launch_bounds__(256) void gcn_head(const ushort* __restrict__ xw_half,
                                                const int* __restrict__ row_start,
                                                const int* __restrict__ csr_src,
                                                const float* __restrict__ dinv,
                                                const float* __restrict__ bc,
                                                const float* __restrict__ Wl,
                                                const float* __restrict__ bl,
                                                float* __restrict__ out) {
    __shared__ int2 lds_ow[4][64];
    const int wid  = threadIdx.x >> 6;
    const int lane = threadIdx.x & 63;
    const int node = blockIdx.x * 4 + wid;
    if (node >= NN) return;
    const int s0 = row_start[node], s1 = row_start[node + 1];
    const float di = dinv[node];
    float ax = 0.f, ay = 0.f;
    const char* xwbase = (const char*)xw_half;
    const uint lane4 = (uint)lane * 4;

#define GCN_BODY(OW)                                            \
    {                                                           \
        uint v = *(const uint*)(xwbase + ((uint)(OW).x + lane4)); \
        float ww = __int_as_float((OW).y);                      \
        FMA_MIX_LO(ax, v, ww); FMA_MIX_HI(ay, v, ww);           \
    }

    for (int e = s0; e < s1; e += 64) {
        const int m = min(64, s1 - e);
        if (lane < m) {
            int s = csr_src[e + lane];
            lds_ow[wid][lane] = make_int2(s * 256, __float_as_int(dinv[s] * di));
        }
        asm volatile("s_waitcnt lgkmcnt(0)" ::: "memory");
        int j = 0;
        for (; j + 8 <= m; j += 8) {
            int2 ow0 = lds_ow[wid][j];
            int2 ow1 = lds_ow[wid][j + 1];
            int2 ow2 = lds_ow[wid][j + 2];
            int2 ow3 = lds_ow[wid][j + 3];
            int2 ow4 = lds_ow[wid][j + 4];
            int2 ow5 = lds_ow[wid][j + 5];
            int2 ow6 = lds_ow[wid][j + 6];
            int2 ow7 = lds_ow[wid][j + 7];
            GCN_BODY(ow0); GCN_BODY(ow1); GCN_BODY(ow2); GCN_BODY(ow3);
            GCN_BODY(ow4); GCN_BODY(ow5); GCN_BODY(ow6); GCN_BODY(ow7);
        }
        for (; j + 4 <= m; j += 4) {
            int2 ow0 = lds_ow[wid][j];
            int2 ow1 = lds_ow[wid][j + 1];
            int2 ow2 = lds_ow[wid][j + 2];
            int2 ow3 = lds_ow[wid][j + 3];
            GCN_BODY(ow0); GCN_BODY(ow1); GCN_BODY(ow2); GCN_BODY(ow3);
        }
        for (; j < m; ++j) {
            int2 ow = lds_ow[wid][j];
            GCN_BODY(ow);
        }
        asm volatile("" ::: "memory");
    }
#undef GCN_BODY
    // xc cols {2*lane, 2*lane+1}
    float2 b = ((const float2*)bc)[lane];
    float o0 = ax + b.x; o0 = o0 > 0.f ? o0 : 0.f;
    float o1 = ay + b.y; o1 = o1 > 0.f ? o1 : 0.f;

    float p[NCLS];
#pragma unroll
    for (int j = 0; j < NCLS; ++j)
        p[j] = o0 * Wl[(2 * lane) * NCLS + j] + o1 * Wl[(2 * lane + 1) * NCLS + j];
#pragma unroll
    for (int m = 32; m >= 1; m >>= 1) {
#pragma unroll
        for (int j = 0; j < NCLS; ++j) p[j] += __shfl_xor(p[j], m, 64);
    }
#pragma unroll
    for (int j = 0; j < NCLS; ++j) p[j] += bl[j];
    float mx = p[0];
#pragma unroll
    for (int j = 1; j < NCLS; ++j) mx = fmaxf(mx, p[j]);
    float s = 0.f;
#pragma unroll
    for (int j = 0; j < NCLS; ++j) s += __expf(p[j] - mx);
    float ls = __logf(s);
    if (lane == 0) {
#pragma unroll
        for (int j = 0; j < NCLS; ++j) out[(size_t)node * NCLS + j] = p[j] - mx - ls;
    }
}

extern "C" void kernel_launch(void* const* d_in, const int* in_sizes, int n_in,
                              void* d_out, int out_size, void* d_ws, size_t ws_size,
                              hipStream_t stream) {
    const float* x       = (const float*)d_in[0];
    const float* Wg      = (const float*)d_in[2];
    const float* att_src = (const float*)d_in[3];
    const float* att_dst = (const float*)d_in[4];
    const float* bg      = (const float*)d_in[5];
    const float* Wc      = (const float*)d_in[6];
    const float* bc      = (const float*)d_in[7];
    const float* Wl      = (const float*)d_in[8];
    const float* bl      = (const float*)d_in[9];
    const int*   ei      = (const int*)d_in[10];
    float* out = (float*)d_out;

    char* p = (char*)d_ws;
    auto alloc = [&](size_t bytes) -> void* {
        void* r = (void*)p;
        p += (bytes + 255) & ~(size_t)255;
        return r;
    };
    ushort* h_half    = (ushort*)alloc((size_t)NN * HC * 2);
    ushort* xg_half   = (ushort*)alloc((size_t)NN * HC * 2);
    ushort* xw_half   = (ushort*)alloc((size_t)NN * HID * 2);
    float*  a_s       = (float*)alloc((size_t)NN * 4 * 4);
    float*  a_d       = (float*)alloc((size_t)NN * 4 * 4);
    int*    deg       = (int*)alloc((size_t)NN * 4);
    float*  dinv      = (float*)alloc((size_t)NN * 4);
    int*    row_start = (int*)alloc((size_t)(NN + 1) * 4);
    int*    cursor    = (int*)alloc((size_t)NN * 4);
    int*    csr_src   = (int*)alloc((size_t)E2 * 4);
    int*    blocksum  = (int*)alloc(256 * 4);
    ushort* wgt       = (ushort*)alloc((size_t)HC * FIN * 2);
    ushort* wct       = (ushort*)alloc((size_t)HID * HC * 2);

    hipMemsetAsync(deg, 0, (size_t)NN * 4, stream);
    hipMemsetAsync(cursor, 0, (size_t)NN * 4, stream);

    prep_kernel<<<128, 256, 0, stream>>>(Wg, Wc, wgt, wct);
    gemm1_mfma<<<1250, 256, 0, stream>>>(x, wgt, att_src, att_dst, h_half, a_s, a_d);

    deg_kernel<<<(EE / 4 + 255) / 256, 256, 0, stream>>>(ei, deg);
    scan_a<<<(NN + 255) / 256, 256, 0, stream>>>(deg, row_start, blocksum);
    scan_b<<<1, 256, 0, stream>>>(blocksum, (NN + 255) / 256);
    scan_c<<<(NN + 255) / 256, 256, 0, stream>>>(row_start, blocksum);
    scatter_kernel<<<(E2 + 255) / 256, 256, 0, stream>>>(ei, row_start, cursor, csr_src);

    gat_half<<<(NN + 3) / 4, 256, 0, stream>>>(h_half, a_s, a_d, row_start, csr_src, bg, xg_half, dinv);
    gemm2_mfma<<<1250, 256, 0, stream>>>(xg_half, wct, xw_half);
    gcn_head<<<(NN + 3) / 4, 256, 0, stream>>>(xw_half, row_start, csr_src, dinv, bc, Wl, bl, out);
}